// Round 12
// baseline (36.258 us; speedup 1.0000x reference)
//
#include <hip/hip_runtime.h>
#include <math.h>

#define BB 32768
#define CC 8
#define HH 128
#define RR 16
#define GG 384
#define ROWS 32
#define NBLK (BB / ROWS)   // 1024

// ---- workspace layout (bytes) ----
#define VTT_OFF   0                          // VtT[128][128] bf16 = 32 KB
#define WT_OFF    (VTT_OFF + 128 * 128 * 2)  // Wt[384][128] bf16 = 96 KB
#define COMB_OFF  (WT_OFF + 384 * 128 * 2)   // comb[8][512] f32  = 16 KB
#define WS_NEEDED (COMB_OFF + 8 * 512 * 4)

typedef short short8 __attribute__((ext_vector_type(8)));
typedef float f32x4  __attribute__((ext_vector_type(4)));

__device__ __forceinline__ unsigned short f2bf(float f) {
    unsigned int u = __float_as_uint(f);
    return (unsigned short)((u + 0x7fffu + ((u >> 16) & 1u)) >> 16);
}
__device__ __forceinline__ float sigmoidf_fast(float v) { return 1.f / (1.f + __expf(-v)); }
__device__ __forceinline__ float tanhf_fast(float v)    { return 2.f / (1.f + __expf(-2.f * v)) - 1.f; }

// ---------------- pass 0: build VtT, Wt (bf16) and comb (f32) ----------------
// VtT[cr][j]  = V[c][j][r]          (cr = c*16+r)   [col][k] layout for MFMA-B
// Wt [g ][cr] = U[c][g][r]                           [col][k] layout for MFMA-B
// comb[c][0:128)=bih_r+bhh_r  [128:256)=bih_z+bhh_z  [256:384)=bhh_n  [384:512)=bih_n
__global__ __launch_bounds__(256) void prep_kernel(
    const float* __restrict__ U, const float* __restrict__ V,
    const float* __restrict__ bih, const float* __restrict__ bhh,
    unsigned short* __restrict__ VtT, unsigned short* __restrict__ Wt,
    float* __restrict__ comb)
{
    const int id = blockIdx.x * 256 + threadIdx.x;
    if (id < 16384) {
        const int cr = id >> 7, j = id & 127;
        VtT[id] = f2bf(V[(cr >> 4) * (HH * RR) + j * RR + (cr & 15)]);
    } else if (id < 16384 + 49152) {
        const int e = id - 16384;
        const int g = e >> 7, cr = e & 127;
        Wt[e] = f2bf(U[(cr >> 4) * (GG * RR) + g * RR + (cr & 15)]);
    } else if (id < 16384 + 49152 + 4096) {
        const int e = id - 65536;
        const int c = e >> 9, s = e & 511;
        const int gate = s >> 7, i = s & 127;
        float v;
        if      (gate == 0) v = bih[c * GG + i]        + bhh[c * GG + i];
        else if (gate == 1) v = bih[c * GG + 128 + i]  + bhh[c * GG + 128 + i];
        else if (gate == 2) v = bhh[c * GG + 256 + i];
        else                v = bih[c * GG + 256 + i];
        comb[e] = v;
    }
}

// ---------------- main kernel: streaming, no bucketing ----------------
// Per block: 32 consecutive rows.
// Phase A: Vh_all[32 x 128] = h[32x128] @ VtT   (Ntile n == condition c)
// Mask:    z[b, c*16+r] = x[b,c] * Vh_all[b, c*16+r]
// Phase B: rec[32 x 384] = z[32x128] @ W
__global__ __launch_bounds__(256) void gru_stream_kernel(
    const float* __restrict__ x, const float* __restrict__ h,
    const unsigned short* __restrict__ VtT, const unsigned short* __restrict__ Wt,
    const float* __restrict__ comb_g, float* __restrict__ out)
{
    __shared__ __align__(16) unsigned short hs[ROWS][HH + 8];  // 8.5 KB
    __shared__ __align__(16) unsigned short zs[ROWS][HH + 8];  // 8.5 KB
    __shared__ float comb_s[CC * 512];                          // 16 KB
    __shared__ int   cs[ROWS];
    __shared__ float wsx[ROWS];

    const int tid  = threadIdx.x;
    const int w    = tid >> 6;     // wave 0..3
    const int lane = tid & 63;
    const int r16  = lane & 15;
    const int hi   = lane >> 4;    // 0..3
    const int row0 = blockIdx.x * ROWS;

    // ---- stage h rows (coalesced, fp32 -> bf16) ----
    {
        const int row = tid >> 3, seg = tid & 7;   // 16 cols per thread
        const float* hp = h + (size_t)(row0 + row) * HH + seg * 16;
        const float4 a0 = *(const float4*)(hp + 0);
        const float4 a1 = *(const float4*)(hp + 4);
        const float4 a2 = *(const float4*)(hp + 8);
        const float4 a3 = *(const float4*)(hp + 12);
        short8 o0, o1;
        o0[0]=(short)f2bf(a0.x); o0[1]=(short)f2bf(a0.y); o0[2]=(short)f2bf(a0.z); o0[3]=(short)f2bf(a0.w);
        o0[4]=(short)f2bf(a1.x); o0[5]=(short)f2bf(a1.y); o0[6]=(short)f2bf(a1.z); o0[7]=(short)f2bf(a1.w);
        o1[0]=(short)f2bf(a2.x); o1[1]=(short)f2bf(a2.y); o1[2]=(short)f2bf(a2.z); o1[3]=(short)f2bf(a2.w);
        o1[4]=(short)f2bf(a3.x); o1[5]=(short)f2bf(a3.y); o1[6]=(short)f2bf(a3.z); o1[7]=(short)f2bf(a3.w);
        *(short8*)&hs[row][seg * 16]     = o0;
        *(short8*)&hs[row][seg * 16 + 8] = o1;
    }

    // ---- per-row condition index + weight from one-hot x ----
    if (tid < ROWS) {
        const float4 x0 = *(const float4*)(x + (size_t)(row0 + tid) * CC);
        const float4 x1 = *(const float4*)(x + (size_t)(row0 + tid) * CC + 4);
        int c = 0; float wv = x0.x;
        if (x0.y != 0.f) { c = 1; wv = x0.y; }
        if (x0.z != 0.f) { c = 2; wv = x0.z; }
        if (x0.w != 0.f) { c = 3; wv = x0.w; }
        if (x1.x != 0.f) { c = 4; wv = x1.x; }
        if (x1.y != 0.f) { c = 5; wv = x1.y; }
        if (x1.z != 0.f) { c = 6; wv = x1.z; }
        if (x1.w != 0.f) { c = 7; wv = x1.w; }
        cs[tid] = c; wsx[tid] = wv;
    }

    // ---- stage comb table (16 KB) ----
    #pragma unroll
    for (int k = 0; k < 4; ++k)
        *(float4*)&comb_s[tid * 16 + k * 4] = *(const float4*)(comb_g + tid * 16 + k * 4);

    __syncthreads();

    // ---- phase A: wave w -> Mtile m = w&1 (16 rows), Ntiles nbase..nbase+3 ----
    {
        const int m = w & 1;
        const int nbase = (w >> 1) * 4;
        f32x4 za[4] = {{0,0,0,0},{0,0,0,0},{0,0,0,0},{0,0,0,0}};
        #pragma unroll
        for (int ks = 0; ks < 4; ++ks) {
            const short8 af = *(const short8*)&hs[m * 16 + r16][ks * 32 + hi * 8];
            #pragma unroll
            for (int nt = 0; nt < 4; ++nt) {
                const short8 bf = *(const short8*)(VtT + ((nbase + nt) * 16 + r16) * HH + ks * 32 + hi * 8);
                za[nt] = __builtin_amdgcn_mfma_f32_16x16x32_bf16(af, bf, za[nt], 0, 0, 0);
            }
        }
        // mask by one-hot weight and write z (acc: col=lane&15, row=4*hi+q)
        #pragma unroll
        for (int q = 0; q < 4; ++q) {
            const int row = m * 16 + 4 * hi + q;
            const int   cr_ = cs[row];
            const float wr_ = wsx[row];
            #pragma unroll
            for (int nt = 0; nt < 4; ++nt) {
                const int ccond = nbase + nt;
                const float wv = (cr_ == ccond) ? wr_ : 0.f;
                zs[row][ccond * 16 + r16] = f2bf(za[nt][q] * wv);
            }
        }
    }
    __syncthreads();

    // ---- phase B: wave w -> i-tiles {2w, 2w+1}, gates r/z/n ----
    short8 az[2][4];   // A-frags: [Mtile][kstep], reused across all 6 col-tiles
    #pragma unroll
    for (int mt = 0; mt < 2; ++mt)
        #pragma unroll
        for (int ks = 0; ks < 4; ++ks)
            az[mt][ks] = *(const short8*)&zs[mt * 16 + r16][ks * 32 + hi * 8];

    #pragma unroll
    for (int d = 0; d < 2; ++d) {
        const int it = (2 * w + d) * 16;       // i-tile base (0..112)
        f32x4 aR[2] = {{0,0,0,0},{0,0,0,0}};
        f32x4 aZ[2] = {{0,0,0,0},{0,0,0,0}};
        f32x4 aN[2] = {{0,0,0,0},{0,0,0,0}};
        #pragma unroll
        for (int ks = 0; ks < 4; ++ks) {
            const short8 bR = *(const short8*)(Wt + (size_t)(0 * HH + it + r16) * HH + ks * 32 + hi * 8);
            const short8 bZ = *(const short8*)(Wt + (size_t)(1 * HH + it + r16) * HH + ks * 32 + hi * 8);
            const short8 bN = *(const short8*)(Wt + (size_t)(2 * HH + it + r16) * HH + ks * 32 + hi * 8);
            #pragma unroll
            for (int mt = 0; mt < 2; ++mt) {
                aR[mt] = __builtin_amdgcn_mfma_f32_16x16x32_bf16(az[mt][ks], bR, aR[mt], 0, 0, 0);
                aZ[mt] = __builtin_amdgcn_mfma_f32_16x16x32_bf16(az[mt][ks], bZ, aZ[mt], 0, 0, 0);
                aN[mt] = __builtin_amdgcn_mfma_f32_16x16x32_bf16(az[mt][ks], bN, aN[mt], 0, 0, 0);
            }
        }
        // epilogue for this i-tile
        const int i = it + r16;
        #pragma unroll
        for (int mt = 0; mt < 2; ++mt) {
            #pragma unroll
            for (int q = 0; q < 4; ++q) {
                const int row  = mt * 16 + 4 * hi + q;
                const int grow = row0 + row;
                const int   c  = cs[row];
                const float wv = wsx[row];
                const float* cb = comb_s + c * 512;
                const float rg = sigmoidf_fast(aR[mt][q] + wv * cb[i]);
                const float zg = sigmoidf_fast(aZ[mt][q] + wv * cb[128 + i]);
                const float ng = tanhf_fast(wv * cb[384 + i] + rg * (aN[mt][q] + wv * cb[256 + i]));
                const float hv = h[(size_t)grow * HH + i];
                out[(size_t)grow * HH + i] = (1.f - zg) * ng + zg * hv;
            }
        }
    }
}

// ---------------- fallback if ws too small ----------------
__global__ __launch_bounds__(128) void gru_cell_naive(
    const float* __restrict__ x, const float* __restrict__ h,
    const float* __restrict__ U, const float* __restrict__ V,
    const float* __restrict__ bias_ih, const float* __restrict__ bias_hh,
    float* __restrict__ out)
{
    const int b = blockIdx.x;
    const int i = threadIdx.x;
    __shared__ float hsn[HH];
    __shared__ float xsn[CC];
    __shared__ float vhn[RR];
    const float h_i = h[b * HH + i];
    hsn[i] = h_i;
    if (i < CC) xsn[i] = x[b * CC + i];
    __syncthreads();
    float g_r = 0.f, g_z = 0.f, g_n = 0.f;
    float bi_r = 0.f, bi_z = 0.f, bi_n = 0.f;
    float bh_r = 0.f, bh_z = 0.f, bh_n = 0.f;
    for (int c = 0; c < CC; ++c) {
        const float w = xsn[c];
        if (w != 0.f) {
            if (i < RR) {
                const float* Vp = V + c * HH * RR + i;
                float a0 = 0.f;
                for (int j = 0; j < HH; ++j) a0 += Vp[j * RR] * hsn[j];
                vhn[i] = a0;
            }
            __syncthreads();
            const float* Up = U + c * 3 * HH * RR;
            float s_r = 0.f, s_z = 0.f, s_n = 0.f;
            for (int r = 0; r < RR; ++r) s_r += Up[i * RR + r] * vhn[r];
            for (int r = 0; r < RR; ++r) s_z += Up[(HH + i) * RR + r] * vhn[r];
            for (int r = 0; r < RR; ++r) s_n += Up[(2 * HH + i) * RR + r] * vhn[r];
            g_r += w * s_r; g_z += w * s_z; g_n += w * s_n;
            bi_r += w * bias_ih[c * GG + i];
            bi_z += w * bias_ih[c * GG + HH + i];
            bi_n += w * bias_ih[c * GG + 2 * HH + i];
            bh_r += w * bias_hh[c * GG + i];
            bh_z += w * bias_hh[c * GG + HH + i];
            bh_n += w * bias_hh[c * GG + 2 * HH + i];
            __syncthreads();
        }
    }
    const float rg = 1.f / (1.f + __expf(-(bi_r + g_r + bh_r)));
    const float zg = 1.f / (1.f + __expf(-(bi_z + g_z + bh_z)));
    const float ng = tanhf(bi_n + rg * (g_n + bh_n));
    out[b * HH + i] = (1.f - zg) * ng + zg * h_i;
}

extern "C" void kernel_launch(void* const* d_in, const int* in_sizes, int n_in,
                              void* d_out, int out_size, void* d_ws, size_t ws_size,
                              hipStream_t stream) {
    const float* x       = (const float*)d_in[0];
    const float* h       = (const float*)d_in[1];
    const float* U       = (const float*)d_in[2];
    const float* V       = (const float*)d_in[3];
    const float* bias_ih = (const float*)d_in[4];
    const float* bias_hh = (const float*)d_in[5];
    float* out = (float*)d_out;

    if (ws_size < (size_t)WS_NEEDED) {
        gru_cell_naive<<<BB, HH, 0, stream>>>(x, h, U, V, bias_ih, bias_hh, out);
        return;
    }

    unsigned short* VtT  = (unsigned short*)((char*)d_ws + VTT_OFF);
    unsigned short* Wt   = (unsigned short*)((char*)d_ws + WT_OFF);
    float*          comb = (float*)((char*)d_ws + COMB_OFF);

    prep_kernel<<<(16384 + 49152 + 4096) / 256, 256, 0, stream>>>(U, V, bias_ih, bias_hh,
                                                                  VtT, Wt, comb);
    gru_stream_kernel<<<NBLK, 256, 0, stream>>>(x, h, VtT, Wt, comb, out);
}